// Round 6
// baseline (96998.907 us; speedup 1.0000x reference)
//
#include <hip/hip_runtime.h>
#include <cstdint>
#include <cstddef>

// GROUND-TRUTH v3: identical to R5 except the OUTPUT is fp32 (reference's
// output dtype is float32; R3-R5's identical failures are explained by the
// harness reading d_out as fp32 while we wrote packed bf16).
// B=4, T=2048, D=1024, H=16, HD=64.
// ws: Q(16MB) + K(16MB) + V(16MB) bf16 = 48MB.  y lives in d_out (fp32);
// proj is in-place on d_out.

typedef __bf16 bf16;

// ---------------------------------------------------------------------------
// Block-cooperative dtype probe of an array's first 1024 dwords.
// packed bf16: bits14..7 of each dword = exponent of even element -> ~1024
//   hits in [96,140].
// fp32 (full precision): bits14..7 = mid-mantissa, ~uniform -> ~180 hits.
// fp32 storing bf16-rounded values: low 16 bits zero -> 0 hits.
// Returns true if the array should be read as fp32.
// ---------------------------------------------------------------------------
__device__ bool probe_is_f32(const void* p, int* red) {
  const unsigned* w = (const unsigned*)p;
  if (threadIdx.x == 0) *red = 0;
  __syncthreads();
  int c = 0;
  for (int i = threadIdx.x; i < 1024; i += blockDim.x) {
    unsigned e = (w[i] >> 7) & 0xFF;
    if (e >= 96 && e <= 140) ++c;
  }
  atomicAdd(red, c);
  __syncthreads();
  bool r = (*red < 512);
  __syncthreads();
  return r;
}

__device__ __forceinline__ float ld2(const void* p, size_t i, bool f32) {
  return f32 ? ((const float*)p)[i] : (float)((const bf16*)p)[i];
}

// ---------------------------------------------------------------------------
// Naive QKV: qkv[m][n] = sum_c x[m][c] * w_qkv[n][c]; scatter to Q/K/V
// [B,H,T,64] bf16 in ws, Q pre-scaled by 1/8.  grid (12, 8192), block 256.
// ---------------------------------------------------------------------------
__global__ void qkv_naive(const void* __restrict__ x, const void* __restrict__ w,
                          bf16* __restrict__ Qo, bf16* __restrict__ Ko,
                          bf16* __restrict__ Vo) {
  __shared__ float xs[1024];
  __shared__ int red;
  const bool xf32 = probe_is_f32(x, &red);
  const bool wf32 = probe_is_f32(w, &red);
  const int m = blockIdx.y;
  const int n = blockIdx.x * 256 + threadIdx.x;
  for (int c = threadIdx.x; c < 1024; c += 256)
    xs[c] = ld2(x, (size_t)m * 1024 + c, xf32);
  __syncthreads();
  float acc = 0.f;
  for (int c = 0; c < 1024; ++c)
    acc += xs[c] * ld2(w, (size_t)n * 1024 + c, wf32);
  const int which = n >> 10;  // 0=Q 1=K 2=V
  bf16* dst = (which == 0) ? Qo : (which == 1) ? Ko : Vo;
  const float scale = (which == 0) ? 0.125f : 1.0f;  // 1/sqrt(64)
  const int n1 = n & 1023;
  const int h = n1 >> 6;
  const int d = n1 & 63;
  const int b = m >> 11;
  const int t = m & 2047;
  dst[(((size_t)(b * 16 + h)) * 2048 + t) * 64 + d] = (bf16)(acc * scale);
}

// ---------------------------------------------------------------------------
// Naive causal attention: one block per (t, bh). Scores in LDS (fp32),
// block-tree softmax, PV by threads 0..63. Writes y[b,t,h*64+d] into d_out
// as FP32.  grid (2048, 64), block 256.
// ---------------------------------------------------------------------------
__global__ void attn_naive(const bf16* __restrict__ Q, const bf16* __restrict__ K,
                           const bf16* __restrict__ V, float* __restrict__ Y) {
  __shared__ float p[2048];
  __shared__ float red[256];
  __shared__ float q[64];
  const int t   = blockIdx.x;
  const int bh  = blockIdx.y;
  const int tid = threadIdx.x;
  const bf16* Qr = Q + ((size_t)bh * 2048 + t) * 64;
  const bf16* Kb = K + (size_t)bh * 2048 * 64;
  const bf16* Vb = V + (size_t)bh * 2048 * 64;

  if (tid < 64) q[tid] = (float)Qr[tid];
  __syncthreads();

  const int nk = t + 1;  // causal: keys 0..t
  float lmax = -1e30f;
  for (int k = tid; k < nk; k += 256) {
    float s = 0.f;
    for (int d = 0; d < 64; ++d) s += q[d] * (float)Kb[(size_t)k * 64 + d];
    p[k] = s;
    lmax = fmaxf(lmax, s);
  }
  red[tid] = lmax;
  __syncthreads();
  for (int o = 128; o > 0; o >>= 1) {
    if (tid < o) red[tid] = fmaxf(red[tid], red[tid + o]);
    __syncthreads();
  }
  const float mx = red[0];
  __syncthreads();

  float lsum = 0.f;
  for (int k = tid; k < nk; k += 256) {
    float e = expf(p[k] - mx);
    p[k] = e;
    lsum += e;
  }
  red[tid] = lsum;
  __syncthreads();
  for (int o = 128; o > 0; o >>= 1) {
    if (tid < o) red[tid] += red[tid + o];
    __syncthreads();
  }
  const float inv = 1.0f / red[0];
  __syncthreads();

  if (tid < 64) {
    float acc = 0.f;
    for (int k = 0; k < nk; ++k) acc += p[k] * (float)Vb[(size_t)k * 64 + tid];
    const int b = bh >> 4;
    const int h = bh & 15;
    Y[((size_t)b * 2048 + t) * 1024 + h * 64 + tid] = acc * inv;
  }
}

// ---------------------------------------------------------------------------
// In-place FP32 projection: one block per row m. Stage full y-row into LDS,
// barrier, overwrite row with out[m][n] = sum_c y[m][c] * w_proj[n][c].
// Row-local -> in-place safe.  grid (8192), block 256; 4 outputs/thread.
// ---------------------------------------------------------------------------
__global__ void proj_inplace(float* __restrict__ yo, const void* __restrict__ w) {
  __shared__ float ys[1024];
  __shared__ int red;
  const bool wf32 = probe_is_f32(w, &red);
  const int m = blockIdx.x;
  float* row = yo + (size_t)m * 1024;
  for (int c = threadIdx.x; c < 1024; c += 256) ys[c] = row[c];
  __syncthreads();   // entire row staged before any overwrite
  float acc[4] = {0.f, 0.f, 0.f, 0.f};
  for (int c = 0; c < 1024; ++c) {
    const float yc = ys[c];
#pragma unroll
    for (int j = 0; j < 4; ++j)
      acc[j] += yc * ld2(w, (size_t)(threadIdx.x + j * 256) * 1024 + c, wf32);
  }
#pragma unroll
  for (int j = 0; j < 4; ++j)
    row[threadIdx.x + j * 256] = acc[j];
}

// ---------------------------------------------------------------------------
extern "C" void kernel_launch(void* const* d_in, const int* in_sizes, int n_in,
                              void* d_out, int out_size, void* d_ws, size_t ws_size,
                              hipStream_t stream) {
  // Permutation-proof input mapping by element count.
  const void* x  = nullptr;   // 4*2048*1024   = 8388608
  const void* wq = nullptr;   // 3072*1024     = 3145728
  const void* wp = nullptr;   // 1024*1024     = 1048576
  for (int i = 0; i < n_in; ++i) {
    if      (in_sizes[i] == 8388608) x  = d_in[i];
    else if (in_sizes[i] == 3145728) wq = d_in[i];
    else if (in_sizes[i] == 1048576) wp = d_in[i];
  }
  if (!x || !wq || !wp) { x = d_in[0]; wq = d_in[1]; wp = d_in[2]; }

  float* out = (float*)d_out;            // [4,2048,1024] fp32
  const size_t NE = (size_t)4 * 16 * 2048 * 64;  // 8388608
  bf16* qb = (bf16*)d_ws;                // [B,H,T,64] bf16
  bf16* kb = qb + NE;
  bf16* vb = kb + NE;                    // total 48MB

  qkv_naive<<<dim3(12, 8192), 256, 0, stream>>>(x, wq, qb, kb, vb);
  attn_naive<<<dim3(2048, 64), 256, 0, stream>>>(qb, kb, vb, out);
  proj_inplace<<<8192, 256, 0, stream>>>(out, wp);
}

// Round 8
// 517.265 us; speedup vs baseline: 187.5228x; 187.5228x over previous
//
#include <hip/hip_runtime.h>
#include <cstdint>
#include <cstddef>

// Optimized pipeline v2. Same kernels as R7; d_out is no longer aliased —
// Q lives in ws (+48MB; ws >= 64MB proven by R1's full-ws run).
// B=4, T=2048, D=1024, H=16, HD=64. Inputs fp32, output fp32.
// ws: K(16MB) + V(16MB) + y(16MB) + Q(16MB) = 64MB. d_out written once (proj).

typedef __bf16 bf16;
typedef __bf16 bf16x8 __attribute__((ext_vector_type(8)));
typedef float  f32x4  __attribute__((ext_vector_type(4)));
typedef float  fvec4  __attribute__((ext_vector_type(4)));

#define MFMA16(a, b, c) __builtin_amdgcn_mfma_f32_16x16x32_bf16((a), (b), (c), 0, 0, 0)

// XOR chunk swizzle for [rows][64] bf16 LDS tiles. 8-elem chunks stay
// contiguous so bf16x8 ops at col%8==0 remain single b128 ops.
__device__ __forceinline__ int swz_off(int row, int col) {
  int sr = (row & 7) ^ ((row >> 3) & 7);
  return row * 64 + ((((col >> 3) ^ sr) & 7) * 8) + (col & 7);
}

__device__ __forceinline__ bf16x8 cvt8(const float* p) {
  fvec4 u = *(const fvec4*)p;
  fvec4 v = *(const fvec4*)(p + 4);
  bf16x8 r;
  r[0] = (bf16)u[0]; r[1] = (bf16)u[1]; r[2] = (bf16)u[2]; r[3] = (bf16)u[3];
  r[4] = (bf16)v[0]; r[5] = (bf16)v[1]; r[6] = (bf16)v[2]; r[7] = (bf16)v[3];
  return r;
}

// ---------------------------------------------------------------------------
// QKV GEMM: qkv[M=8192, N=3072] = x[8192,1024] * w_qkv[3072,1024]^T
// fp32 inputs, register-convert staging, 128x128 tile, BK=32, 4 waves.
// Epilogue scatters to Q/K/V [B,H,T,64] bf16; Q *= 0.125.  grid (24,64).
// ---------------------------------------------------------------------------
__global__ __launch_bounds__(256, 2)
void gemm_qkv(const float* __restrict__ A, const float* __restrict__ B,
              bf16* __restrict__ Qo, bf16* __restrict__ Ko,
              bf16* __restrict__ Vo) {
  __shared__ __align__(16) bf16 As[128 * 32];
  __shared__ __align__(16) bf16 Bs[128 * 32];
  const int K = 1024;

  const int tid  = threadIdx.x;
  const int lane = tid & 63;
  const int wave = tid >> 6;
  const int quad = lane >> 4;
  const int l15  = lane & 15;
  const int wm   = (wave >> 1) * 64;
  const int wn   = (wave & 1) * 64;
  const int m0   = blockIdx.y * 128;
  const int n0   = blockIdx.x * 128;

  f32x4 acc[4][4];
#pragma unroll
  for (int i = 0; i < 4; ++i)
#pragma unroll
    for (int j = 0; j < 4; ++j) acc[i][j] = f32x4{0.f, 0.f, 0.f, 0.f};

  const int r0 = tid >> 2;
  const int c0 = (tid & 3) * 8;
  const size_t aoff0 = (size_t)(m0 + r0) * K + c0;
  const size_t aoff1 = (size_t)(m0 + 64 + r0) * K + c0;
  const size_t boff0 = (size_t)(n0 + r0) * K + c0;
  const size_t boff1 = (size_t)(n0 + 64 + r0) * K + c0;

  for (int k0 = 0; k0 < K; k0 += 32) {
    bf16x8 va0 = cvt8(A + aoff0 + k0);
    bf16x8 va1 = cvt8(A + aoff1 + k0);
    bf16x8 vb0 = cvt8(B + boff0 + k0);
    bf16x8 vb1 = cvt8(B + boff1 + k0);
    __syncthreads();
    *(bf16x8*)(As + tid * 8)        = va0;
    *(bf16x8*)(As + 2048 + tid * 8) = va1;
    *(bf16x8*)(Bs + tid * 8)        = vb0;
    *(bf16x8*)(Bs + 2048 + tid * 8) = vb1;
    __syncthreads();

    bf16x8 af[4], bfr[4];
#pragma unroll
    for (int i = 0; i < 4; ++i)
      af[i] = *(const bf16x8*)(As + (wm + i * 16 + l15) * 32 + quad * 8);
#pragma unroll
    for (int j = 0; j < 4; ++j)
      bfr[j] = *(const bf16x8*)(Bs + (wn + j * 16 + l15) * 32 + quad * 8);
#pragma unroll
    for (int i = 0; i < 4; ++i)
#pragma unroll
      for (int j = 0; j < 4; ++j)
        acc[i][j] = MFMA16(af[i], bfr[j], acc[i][j]);
  }

  // C/D layout: col = lane&15, row = quad*4 + reg
  const int which = n0 >> 10;  // 0=Q 1=K 2=V
  bf16* dst = (which == 0) ? Qo : (which == 1) ? Ko : Vo;
  const float scale = (which == 0) ? 0.125f : 1.0f;  // 1/sqrt(64)
#pragma unroll
  for (int i = 0; i < 4; ++i) {
    const int m = m0 + wm + i * 16 + quad * 4;
#pragma unroll
    for (int j = 0; j < 4; ++j) {
      const int n  = n0 + wn + j * 16 + l15;
      const int n1 = n & 1023;
      const int h  = n1 >> 6;
      const int d  = n1 & 63;
#pragma unroll
      for (int r = 0; r < 4; ++r) {
        const int mm = m + r;
        const int b  = mm >> 11;
        const int t  = mm & 2047;
        dst[(((size_t)(b * 16 + h)) * 2048 + t) * 64 + d] =
            (bf16)(acc[i][j][r] * scale);
      }
    }
  }
}

// ---------------------------------------------------------------------------
// Flash attention, causal. Block = (qt, bh): 64 q-rows; 4 waves x 16 q-rows.
// Q pre-scaled by 1/8. Online softmax in exp2 domain. grid (32,64).
// ---------------------------------------------------------------------------
__global__ __launch_bounds__(256, 2)
void attn(const bf16* __restrict__ Q, const bf16* __restrict__ Kk,
          const bf16* __restrict__ V, bf16* __restrict__ Y) {
  __shared__ __align__(16) bf16 Ks[64 * 64];       // [kv][d] chunk-swizzled
  __shared__ __align__(16) bf16 Vt[64 * 64];       // [d][kv] chunk-swizzled
  __shared__ __align__(16) bf16 Ps[4 * 16 * 64];   // per-wave P strips

  const int tid  = threadIdx.x;
  const int wave = tid >> 6;
  const int lane = tid & 63;
  const int quad = lane >> 4;
  const int l15  = lane & 15;
  const int qt   = blockIdx.x;
  const int bh   = blockIdx.y;
  const int q0   = qt * 64;
  const int b    = bh >> 4;
  const int h    = bh & 15;
  const bf16* Qb = Q  + (size_t)bh * (2048 * 64);
  const bf16* Kb = Kk + (size_t)bh * (2048 * 64);
  const bf16* Vb = V  + (size_t)bh * (2048 * 64);

  bf16x8 qa[2];
#pragma unroll
  for (int t = 0; t < 2; ++t)
    qa[t] = *(const bf16x8*)(Qb + (size_t)(q0 + wave * 16 + l15) * 64 + t * 32 + quad * 8);

  const float NEG = -1e30f;
  f32x4 m_run = {NEG, NEG, NEG, NEG};
  f32x4 l_run = {0.f, 0.f, 0.f, 0.f};
  f32x4 o[4];
#pragma unroll
  for (int j = 0; j < 4; ++j) o[j] = f32x4{0.f, 0.f, 0.f, 0.f};

  bf16* Pw = Ps + wave * (16 * 64);

  const int vr = tid >> 2;
  const int vc = (tid & 3) * 16;

  for (int kt = 0; kt <= qt; ++kt) {
    const int k0 = kt * 64;
    __syncthreads();
    {
      bf16x8 kv0 = *(const bf16x8*)(Kb + (size_t)(k0 + vr) * 64 + vc);
      bf16x8 kv1 = *(const bf16x8*)(Kb + (size_t)(k0 + vr) * 64 + vc + 8);
      bf16x8 vv0 = *(const bf16x8*)(Vb + (size_t)(k0 + vr) * 64 + vc);
      bf16x8 vv1 = *(const bf16x8*)(Vb + (size_t)(k0 + vr) * 64 + vc + 8);
      *(bf16x8*)(Ks + swz_off(vr, vc))     = kv0;
      *(bf16x8*)(Ks + swz_off(vr, vc + 8)) = kv1;
#pragma unroll
      for (int i = 0; i < 8; ++i) Vt[swz_off(vc + i, vr)]     = vv0[i];
#pragma unroll
      for (int i = 0; i < 8; ++i) Vt[swz_off(vc + 8 + i, vr)] = vv1[i];
    }
    __syncthreads();

    f32x4 s[4];
#pragma unroll
    for (int j = 0; j < 4; ++j) {
      const int kvr = j * 16 + l15;
      bf16x8 k0f = *(const bf16x8*)(Ks + swz_off(kvr, quad * 8));
      bf16x8 k1f = *(const bf16x8*)(Ks + swz_off(kvr, 32 + quad * 8));
      f32x4 z = {0.f, 0.f, 0.f, 0.f};
      z = MFMA16(qa[0], k0f, z);
      z = MFMA16(qa[1], k1f, z);
      s[j] = z;
    }
#pragma unroll
    for (int j = 0; j < 4; ++j)
#pragma unroll
      for (int r = 0; r < 4; ++r) s[j][r] *= 1.44269504f;

    if (kt == qt) {
#pragma unroll
      for (int j = 0; j < 4; ++j) {
        const int kvg = k0 + j * 16 + l15;
#pragma unroll
        for (int r = 0; r < 4; ++r) {
          const int qg = q0 + wave * 16 + quad * 4 + r;
          if (kvg > qg) s[j][r] = NEG;
        }
      }
    }

    f32x4 tm;
#pragma unroll
    for (int r = 0; r < 4; ++r)
      tm[r] = fmaxf(fmaxf(s[0][r], s[1][r]), fmaxf(s[2][r], s[3][r]));
#pragma unroll
    for (int msk = 1; msk < 16; msk <<= 1)
#pragma unroll
      for (int r = 0; r < 4; ++r)
        tm[r] = fmaxf(tm[r], __shfl_xor(tm[r], msk));

    f32x4 mn, al;
#pragma unroll
    for (int r = 0; r < 4; ++r) {
      mn[r] = fmaxf(m_run[r], tm[r]);
      al[r] = exp2f(m_run[r] - mn[r]);
      m_run[r] = mn[r];
    }

    f32x4 rs = {0.f, 0.f, 0.f, 0.f};
#pragma unroll
    for (int j = 0; j < 4; ++j)
#pragma unroll
      for (int r = 0; r < 4; ++r) {
        float p = exp2f(s[j][r] - mn[r]);
        s[j][r] = p;
        rs[r] += p;
      }
#pragma unroll
    for (int msk = 1; msk < 16; msk <<= 1)
#pragma unroll
      for (int r = 0; r < 4; ++r) rs[r] += __shfl_xor(rs[r], msk);
#pragma unroll
    for (int r = 0; r < 4; ++r) l_run[r] = l_run[r] * al[r] + rs[r];
#pragma unroll
    for (int j = 0; j < 4; ++j)
#pragma unroll
      for (int r = 0; r < 4; ++r) o[j][r] *= al[r];

#pragma unroll
    for (int j = 0; j < 4; ++j)
#pragma unroll
      for (int r = 0; r < 4; ++r)
        Pw[swz_off(quad * 4 + r, j * 16 + l15)] = (bf16)s[j][r];

    bf16x8 pf0 = *(const bf16x8*)(Pw + swz_off(l15, quad * 8));
    bf16x8 pf1 = *(const bf16x8*)(Pw + swz_off(l15, 32 + quad * 8));
#pragma unroll
    for (int j = 0; j < 4; ++j) {
      const int d = j * 16 + l15;
      bf16x8 vf0 = *(const bf16x8*)(Vt + swz_off(d, quad * 8));
      bf16x8 vf1 = *(const bf16x8*)(Vt + swz_off(d, 32 + quad * 8));
      o[j] = MFMA16(pf0, vf0, o[j]);
      o[j] = MFMA16(pf1, vf1, o[j]);
    }
  }

#pragma unroll
  for (int j = 0; j < 4; ++j) {
    const int dcol = h * 64 + j * 16 + l15;
#pragma unroll
    for (int r = 0; r < 4; ++r) {
      const int trow = q0 + wave * 16 + quad * 4 + r;
      Y[((size_t)b * 2048 + trow) * 1024 + dcol] = (bf16)(o[j][r] / l_run[r]);
    }
  }
}

// ---------------------------------------------------------------------------
// Projection GEMM: out[8192,1024] fp32 = y[8192,1024](bf16) * w_proj[1024,1024]^T
// A: bf16 vector loads; B: fp32 cvt8 staging.  grid (8,64).
// ---------------------------------------------------------------------------
__global__ __launch_bounds__(256, 2)
void gemm_proj(const bf16* __restrict__ A, const float* __restrict__ B,
               float* __restrict__ C) {
  __shared__ __align__(16) bf16 As[128 * 32];
  __shared__ __align__(16) bf16 Bs[128 * 32];
  const int K = 1024, N = 1024;

  const int tid  = threadIdx.x;
  const int lane = tid & 63;
  const int wave = tid >> 6;
  const int quad = lane >> 4;
  const int l15  = lane & 15;
  const int wm   = (wave >> 1) * 64;
  const int wn   = (wave & 1) * 64;
  const int m0   = blockIdx.y * 128;
  const int n0   = blockIdx.x * 128;

  f32x4 acc[4][4];
#pragma unroll
  for (int i = 0; i < 4; ++i)
#pragma unroll
    for (int j = 0; j < 4; ++j) acc[i][j] = f32x4{0.f, 0.f, 0.f, 0.f};

  const int r0 = tid >> 2;
  const int c0 = (tid & 3) * 8;
  const size_t aoff0 = (size_t)(m0 + r0) * K + c0;
  const size_t aoff1 = (size_t)(m0 + 64 + r0) * K + c0;
  const size_t boff0 = (size_t)(n0 + r0) * K + c0;
  const size_t boff1 = (size_t)(n0 + 64 + r0) * K + c0;

  for (int k0 = 0; k0 < K; k0 += 32) {
    bf16x8 va0 = *(const bf16x8*)(A + aoff0 + k0);
    bf16x8 va1 = *(const bf16x8*)(A + aoff1 + k0);
    bf16x8 vb0 = cvt8(B + boff0 + k0);
    bf16x8 vb1 = cvt8(B + boff1 + k0);
    __syncthreads();
    *(bf16x8*)(As + tid * 8)        = va0;
    *(bf16x8*)(As + 2048 + tid * 8) = va1;
    *(bf16x8*)(Bs + tid * 8)        = vb0;
    *(bf16x8*)(Bs + 2048 + tid * 8) = vb1;
    __syncthreads();

    bf16x8 af[4], bfr[4];
#pragma unroll
    for (int i = 0; i < 4; ++i)
      af[i] = *(const bf16x8*)(As + (wm + i * 16 + l15) * 32 + quad * 8);
#pragma unroll
    for (int j = 0; j < 4; ++j)
      bfr[j] = *(const bf16x8*)(Bs + (wn + j * 16 + l15) * 32 + quad * 8);
#pragma unroll
    for (int i = 0; i < 4; ++i)
#pragma unroll
      for (int j = 0; j < 4; ++j)
        acc[i][j] = MFMA16(af[i], bfr[j], acc[i][j]);
  }

#pragma unroll
  for (int i = 0; i < 4; ++i) {
    const int m = m0 + wm + i * 16 + quad * 4;
#pragma unroll
    for (int j = 0; j < 4; ++j) {
      const int n = n0 + wn + j * 16 + l15;
#pragma unroll
      for (int r = 0; r < 4; ++r)
        C[(size_t)(m + r) * N + n] = acc[i][j][r];
    }
  }
}

// ---------------------------------------------------------------------------
extern "C" void kernel_launch(void* const* d_in, const int* in_sizes, int n_in,
                              void* d_out, int out_size, void* d_ws, size_t ws_size,
                              hipStream_t stream) {
  const float* x  = nullptr;   // 8388608 elems
  const float* wq = nullptr;   // 3145728
  const float* wp = nullptr;   // 1048576
  for (int i = 0; i < n_in; ++i) {
    if      (in_sizes[i] == 8388608) x  = (const float*)d_in[i];
    else if (in_sizes[i] == 3145728) wq = (const float*)d_in[i];
    else if (in_sizes[i] == 1048576) wp = (const float*)d_in[i];
  }
  if (!x || !wq || !wp) {
    x = (const float*)d_in[0]; wq = (const float*)d_in[1]; wp = (const float*)d_in[2];
  }

  float* out = (float*)d_out;            // [4,2048,1024] fp32 (32MB), written once
  const size_t NE = (size_t)4 * 16 * 2048 * 64;  // 8388608
  bf16* kb = (bf16*)d_ws;                // ws: K(16) + V(16) + y(16) + Q(16) = 64MB
  bf16* vb = kb + NE;
  bf16* yb = vb + NE;
  bf16* qb = yb + NE;

  gemm_qkv<<<dim3(24, 64), 256, 0, stream>>>(x, wq, qb, kb, vb);
  attn<<<dim3(32, 64), 256, 0, stream>>>(qb, kb, vb, yb);
  gemm_proj<<<dim3(8, 64), 256, 0, stream>>>(yb, wp, out);
}

// Round 9
// 337.956 us; speedup vs baseline: 287.0162x; 1.5306x over previous
//
#include <hip/hip_runtime.h>
#include <cstdint>
#include <cstddef>

// Pipeline v3: gemm_qkv + gemm_proj unchanged (validated, R8). attn rewritten:
// pair-balanced grid (block p handles q-tiles {p, 31-p} -> 33 k-tiles each),
// double-buffered LDS with register prefetch (1 barrier/k-tile), vectorized
// pack-transpose for V staging.
// B=4, T=2048, D=1024, H=16, HD=64. Inputs fp32, output fp32.
// ws: K(16MB) + V(16MB) + y(16MB) + Q(16MB) = 64MB. d_out written once (proj).

typedef __bf16 bf16;
typedef __bf16 bf16x8 __attribute__((ext_vector_type(8)));
typedef float  f32x4  __attribute__((ext_vector_type(4)));
typedef float  fvec4  __attribute__((ext_vector_type(4)));
typedef unsigned u32x4 __attribute__((ext_vector_type(4)));

#define MFMA16(a, b, c) __builtin_amdgcn_mfma_f32_16x16x32_bf16((a), (b), (c), 0, 0, 0)

// XOR chunk swizzle for [rows][64] bf16 LDS tiles. 8-elem chunks stay
// contiguous so bf16x8 ops at col%8==0 remain single b128 ops.
__device__ __forceinline__ int swz_off(int row, int col) {
  int sr = (row & 7) ^ ((row >> 3) & 7);
  return row * 64 + ((((col >> 3) ^ sr) & 7) * 8) + (col & 7);
}

__device__ __forceinline__ bf16x8 cvt8(const float* p) {
  fvec4 u = *(const fvec4*)p;
  fvec4 v = *(const fvec4*)(p + 4);
  bf16x8 r;
  r[0] = (bf16)u[0]; r[1] = (bf16)u[1]; r[2] = (bf16)u[2]; r[3] = (bf16)u[3];
  r[4] = (bf16)v[0]; r[5] = (bf16)v[1]; r[6] = (bf16)v[2]; r[7] = (bf16)v[3];
  return r;
}

// ---------------------------------------------------------------------------
// QKV GEMM (unchanged from R8): qkv[8192,3072] = x * w_qkv^T, scatter to
// Q/K/V [B,H,T,64] bf16; Q *= 0.125.  grid (24,64).
// ---------------------------------------------------------------------------
__global__ __launch_bounds__(256, 2)
void gemm_qkv(const float* __restrict__ A, const float* __restrict__ B,
              bf16* __restrict__ Qo, bf16* __restrict__ Ko,
              bf16* __restrict__ Vo) {
  __shared__ __align__(16) bf16 As[128 * 32];
  __shared__ __align__(16) bf16 Bs[128 * 32];
  const int K = 1024;

  const int tid  = threadIdx.x;
  const int lane = tid & 63;
  const int wave = tid >> 6;
  const int quad = lane >> 4;
  const int l15  = lane & 15;
  const int wm   = (wave >> 1) * 64;
  const int wn   = (wave & 1) * 64;
  const int m0   = blockIdx.y * 128;
  const int n0   = blockIdx.x * 128;

  f32x4 acc[4][4];
#pragma unroll
  for (int i = 0; i < 4; ++i)
#pragma unroll
    for (int j = 0; j < 4; ++j) acc[i][j] = f32x4{0.f, 0.f, 0.f, 0.f};

  const int r0 = tid >> 2;
  const int c0 = (tid & 3) * 8;
  const size_t aoff0 = (size_t)(m0 + r0) * K + c0;
  const size_t aoff1 = (size_t)(m0 + 64 + r0) * K + c0;
  const size_t boff0 = (size_t)(n0 + r0) * K + c0;
  const size_t boff1 = (size_t)(n0 + 64 + r0) * K + c0;

  for (int k0 = 0; k0 < K; k0 += 32) {
    bf16x8 va0 = cvt8(A + aoff0 + k0);
    bf16x8 va1 = cvt8(A + aoff1 + k0);
    bf16x8 vb0 = cvt8(B + boff0 + k0);
    bf16x8 vb1 = cvt8(B + boff1 + k0);
    __syncthreads();
    *(bf16x8*)(As + tid * 8)        = va0;
    *(bf16x8*)(As + 2048 + tid * 8) = va1;
    *(bf16x8*)(Bs + tid * 8)        = vb0;
    *(bf16x8*)(Bs + 2048 + tid * 8) = vb1;
    __syncthreads();

    bf16x8 af[4], bfr[4];
#pragma unroll
    for (int i = 0; i < 4; ++i)
      af[i] = *(const bf16x8*)(As + (wm + i * 16 + l15) * 32 + quad * 8);
#pragma unroll
    for (int j = 0; j < 4; ++j)
      bfr[j] = *(const bf16x8*)(Bs + (wn + j * 16 + l15) * 32 + quad * 8);
#pragma unroll
    for (int i = 0; i < 4; ++i)
#pragma unroll
      for (int j = 0; j < 4; ++j)
        acc[i][j] = MFMA16(af[i], bfr[j], acc[i][j]);
  }

  const int which = n0 >> 10;  // 0=Q 1=K 2=V
  bf16* dst = (which == 0) ? Qo : (which == 1) ? Ko : Vo;
  const float scale = (which == 0) ? 0.125f : 1.0f;  // 1/sqrt(64)
#pragma unroll
  for (int i = 0; i < 4; ++i) {
    const int m = m0 + wm + i * 16 + quad * 4;
#pragma unroll
    for (int j = 0; j < 4; ++j) {
      const int n  = n0 + wn + j * 16 + l15;
      const int n1 = n & 1023;
      const int h  = n1 >> 6;
      const int d  = n1 & 63;
#pragma unroll
      for (int r = 0; r < 4; ++r) {
        const int mm = m + r;
        const int b  = mm >> 11;
        const int t  = mm & 2047;
        dst[(((size_t)(b * 16 + h)) * 2048 + t) * 64 + d] =
            (bf16)(acc[i][j][r] * scale);
      }
    }
  }
}

// ---------------------------------------------------------------------------
// Flash attention v2, causal. Block p in grid (16,64) handles q-tiles
// {p, 31-p} for one (b,h): 33 k-tiles total (balanced). Double-buffered LDS,
// register prefetch, one barrier per k-tile. 4 waves x 16 q-rows.
// ---------------------------------------------------------------------------
__global__ __launch_bounds__(256, 2)
void attn(const bf16* __restrict__ Q, const bf16* __restrict__ Kk,
          const bf16* __restrict__ V, bf16* __restrict__ Y) {
  __shared__ __align__(16) bf16 Ks[2][64 * 64];    // [kv][d] chunk-swizzled
  __shared__ __align__(16) bf16 Vt[2][64 * 64];    // [d][kv] chunk-swizzled
  __shared__ __align__(16) bf16 Ps[4 * 16 * 64];   // per-wave P strips

  const int tid  = threadIdx.x;
  const int wave = tid >> 6;
  const int lane = tid & 63;
  const int quad = lane >> 4;
  const int l15  = lane & 15;
  const int bh   = blockIdx.y;
  const int b    = bh >> 4;
  const int h    = bh & 15;
  const bf16* Qb = Q  + (size_t)bh * (2048 * 64);
  const bf16* Kb = Kk + (size_t)bh * (2048 * 64);
  const bf16* Vb = V  + (size_t)bh * (2048 * 64);
  bf16* Pw = Ps + wave * (16 * 64);

  // staging thread mapping
  const int kr = tid >> 2;          // K: row 0..63
  const int kc = (tid & 3) * 16;    // K: col group
  const int vp = tid >> 3;          // V: row-pair 0..31
  const int vc8 = (tid & 7) * 8;    // V: col chunk base

  const float NEG = -1e30f;

#pragma unroll 1
  for (int pass = 0; pass < 2; ++pass) {
    const int qt = pass ? (31 - (int)blockIdx.x) : (int)blockIdx.x;
    const int q0 = qt * 64;

    bf16x8 qa[2];
#pragma unroll
    for (int t = 0; t < 2; ++t)
      qa[t] = *(const bf16x8*)(Qb + (size_t)(q0 + wave * 16 + l15) * 64 + t * 32 + quad * 8);

    f32x4 m_run = {NEG, NEG, NEG, NEG};
    f32x4 l_run = {0.f, 0.f, 0.f, 0.f};
    f32x4 o[4];
#pragma unroll
    for (int j = 0; j < 4; ++j) o[j] = f32x4{0.f, 0.f, 0.f, 0.f};

    // prefetch tile 0 into regs
    bf16x8 pk0 = *(const bf16x8*)(Kb + (size_t)kr * 64 + kc);
    bf16x8 pk1 = *(const bf16x8*)(Kb + (size_t)kr * 64 + kc + 8);
    u32x4  pva = *(const u32x4*)(Vb + (size_t)(2 * vp) * 64 + vc8);
    u32x4  pvb = *(const u32x4*)(Vb + (size_t)(2 * vp + 1) * 64 + vc8);

#pragma unroll 1
    for (int kt = 0; kt <= qt; ++kt) {
      const int cur = kt & 1;
      const int k0  = kt * 64;
      // write prefetched tile -> LDS[cur] (vmcnt wait folds here)
      *(bf16x8*)(Ks[cur] + swz_off(kr, kc))     = pk0;
      *(bf16x8*)(Ks[cur] + swz_off(kr, kc + 8)) = pk1;
      {
        unsigned* vt32 = (unsigned*)Vt[cur];
#pragma unroll
        for (int i = 0; i < 8; ++i) {
          unsigned lo = (i & 1) ? (pva[i >> 1] >> 16) : (pva[i >> 1] & 0xFFFFu);
          unsigned hi = (i & 1) ? (pvb[i >> 1] >> 16) : (pvb[i >> 1] & 0xFFFFu);
          vt32[swz_off(vc8 + i, 2 * vp) >> 1] = lo | (hi << 16);
        }
      }
      __syncthreads();

      // prefetch tile kt+1 (consumed at next iteration's LDS write)
      if (kt < qt) {
        const int kn = k0 + 64;
        pk0 = *(const bf16x8*)(Kb + (size_t)(kn + kr) * 64 + kc);
        pk1 = *(const bf16x8*)(Kb + (size_t)(kn + kr) * 64 + kc + 8);
        pva = *(const u32x4*)(Vb + (size_t)(kn + 2 * vp) * 64 + vc8);
        pvb = *(const u32x4*)(Vb + (size_t)(kn + 2 * vp + 1) * 64 + vc8);
      }

      // S = Q K^T : 16 q-rows x 64 kv
      f32x4 s[4];
#pragma unroll
      for (int j = 0; j < 4; ++j) {
        const int kvr = j * 16 + l15;
        bf16x8 k0f = *(const bf16x8*)(Ks[cur] + swz_off(kvr, quad * 8));
        bf16x8 k1f = *(const bf16x8*)(Ks[cur] + swz_off(kvr, 32 + quad * 8));
        f32x4 z = {0.f, 0.f, 0.f, 0.f};
        z = MFMA16(qa[0], k0f, z);
        z = MFMA16(qa[1], k1f, z);
        s[j] = z;
      }
#pragma unroll
      for (int j = 0; j < 4; ++j)
#pragma unroll
        for (int r = 0; r < 4; ++r) s[j][r] *= 1.44269504f;  // log2 domain

      if (kt == qt) {  // diagonal: causal mask
#pragma unroll
        for (int j = 0; j < 4; ++j) {
          const int kvg = k0 + j * 16 + l15;
#pragma unroll
          for (int r = 0; r < 4; ++r) {
            const int qg = q0 + wave * 16 + quad * 4 + r;
            if (kvg > qg) s[j][r] = NEG;
          }
        }
      }

      f32x4 tm;
#pragma unroll
      for (int r = 0; r < 4; ++r)
        tm[r] = fmaxf(fmaxf(s[0][r], s[1][r]), fmaxf(s[2][r], s[3][r]));
#pragma unroll
      for (int msk = 1; msk < 16; msk <<= 1)
#pragma unroll
        for (int r = 0; r < 4; ++r)
          tm[r] = fmaxf(tm[r], __shfl_xor(tm[r], msk));

      f32x4 mn, al;
#pragma unroll
      for (int r = 0; r < 4; ++r) {
        mn[r] = fmaxf(m_run[r], tm[r]);
        al[r] = exp2f(m_run[r] - mn[r]);
        m_run[r] = mn[r];
      }

      f32x4 rs = {0.f, 0.f, 0.f, 0.f};
#pragma unroll
      for (int j = 0; j < 4; ++j)
#pragma unroll
        for (int r = 0; r < 4; ++r) {
          float p = exp2f(s[j][r] - mn[r]);
          s[j][r] = p;
          rs[r] += p;
        }
#pragma unroll
      for (int msk = 1; msk < 16; msk <<= 1)
#pragma unroll
        for (int r = 0; r < 4; ++r) rs[r] += __shfl_xor(rs[r], msk);
#pragma unroll
      for (int r = 0; r < 4; ++r) l_run[r] = l_run[r] * al[r] + rs[r];
#pragma unroll
      for (int j = 0; j < 4; ++j)
#pragma unroll
        for (int r = 0; r < 4; ++r) o[j][r] *= al[r];

      // P: C-layout regs -> per-wave LDS strip -> A-operand frags
#pragma unroll
      for (int j = 0; j < 4; ++j)
#pragma unroll
        for (int r = 0; r < 4; ++r)
          Pw[swz_off(quad * 4 + r, j * 16 + l15)] = (bf16)s[j][r];

      bf16x8 pf0 = *(const bf16x8*)(Pw + swz_off(l15, quad * 8));
      bf16x8 pf1 = *(const bf16x8*)(Pw + swz_off(l15, 32 + quad * 8));
#pragma unroll
      for (int j = 0; j < 4; ++j) {
        const int d = j * 16 + l15;
        bf16x8 vf0 = *(const bf16x8*)(Vt[cur] + swz_off(d, quad * 8));
        bf16x8 vf1 = *(const bf16x8*)(Vt[cur] + swz_off(d, 32 + quad * 8));
        o[j] = MFMA16(pf0, vf0, o[j]);
        o[j] = MFMA16(pf1, vf1, o[j]);
      }
    }

    // finalize: divide by l, write y[b][t][h*64+d]
#pragma unroll
    for (int j = 0; j < 4; ++j) {
      const int dcol = h * 64 + j * 16 + l15;
#pragma unroll
      for (int r = 0; r < 4; ++r) {
        const int trow = q0 + wave * 16 + quad * 4 + r;
        Y[((size_t)b * 2048 + trow) * 1024 + dcol] = (bf16)(o[j][r] / l_run[r]);
      }
    }
    __syncthreads();  // pass boundary: protect LDS buffers for next pass
  }
}

// ---------------------------------------------------------------------------
// Projection GEMM (unchanged from R8): out[8192,1024] fp32 = y(bf16) * w^T.
// grid (8,64).
// ---------------------------------------------------------------------------
__global__ __launch_bounds__(256, 2)
void gemm_proj(const bf16* __restrict__ A, const float* __restrict__ B,
               float* __restrict__ C) {
  __shared__ __align__(16) bf16 As[128 * 32];
  __shared__ __align__(16) bf16 Bs[128 * 32];
  const int K = 1024, N = 1024;

  const int tid  = threadIdx.x;
  const int lane = tid & 63;
  const int wave = tid >> 6;
  const int quad = lane >> 4;
  const int l15  = lane & 15;
  const int wm   = (wave >> 1) * 64;
  const int wn   = (wave & 1) * 64;
  const int m0   = blockIdx.y * 128;
  const int n0   = blockIdx.x * 128;

  f32x4 acc[4][4];
#pragma unroll
  for (int i = 0; i < 4; ++i)
#pragma unroll
    for (int j = 0; j < 4; ++j) acc[i][j] = f32x4{0.f, 0.f, 0.f, 0.f};

  const int r0 = tid >> 2;
  const int c0 = (tid & 3) * 8;
  const size_t aoff0 = (size_t)(m0 + r0) * K + c0;
  const size_t aoff1 = (size_t)(m0 + 64 + r0) * K + c0;
  const size_t boff0 = (size_t)(n0 + r0) * K + c0;
  const size_t boff1 = (size_t)(n0 + 64 + r0) * K + c0;

  for (int k0 = 0; k0 < K; k0 += 32) {
    bf16x8 va0 = *(const bf16x8*)(A + aoff0 + k0);
    bf16x8 va1 = *(const bf16x8*)(A + aoff1 + k0);
    bf16x8 vb0 = cvt8(B + boff0 + k0);
    bf16x8 vb1 = cvt8(B + boff1 + k0);
    __syncthreads();
    *(bf16x8*)(As + tid * 8)        = va0;
    *(bf16x8*)(As + 2048 + tid * 8) = va1;
    *(bf16x8*)(Bs + tid * 8)        = vb0;
    *(bf16x8*)(Bs + 2048 + tid * 8) = vb1;
    __syncthreads();

    bf16x8 af[4], bfr[4];
#pragma unroll
    for (int i = 0; i < 4; ++i)
      af[i] = *(const bf16x8*)(As + (wm + i * 16 + l15) * 32 + quad * 8);
#pragma unroll
    for (int j = 0; j < 4; ++j)
      bfr[j] = *(const bf16x8*)(Bs + (wn + j * 16 + l15) * 32 + quad * 8);
#pragma unroll
    for (int i = 0; i < 4; ++i)
#pragma unroll
      for (int j = 0; j < 4; ++j)
        acc[i][j] = MFMA16(af[i], bfr[j], acc[i][j]);
  }

#pragma unroll
  for (int i = 0; i < 4; ++i) {
    const int m = m0 + wm + i * 16 + quad * 4;
#pragma unroll
    for (int j = 0; j < 4; ++j) {
      const int n = n0 + wn + j * 16 + l15;
#pragma unroll
      for (int r = 0; r < 4; ++r)
        C[(size_t)(m + r) * N + n] = acc[i][j][r];
    }
  }
}

// ---------------------------------------------------------------------------
extern "C" void kernel_launch(void* const* d_in, const int* in_sizes, int n_in,
                              void* d_out, int out_size, void* d_ws, size_t ws_size,
                              hipStream_t stream) {
  const float* x  = nullptr;   // 8388608 elems
  const float* wq = nullptr;   // 3145728
  const float* wp = nullptr;   // 1048576
  for (int i = 0; i < n_in; ++i) {
    if      (in_sizes[i] == 8388608) x  = (const float*)d_in[i];
    else if (in_sizes[i] == 3145728) wq = (const float*)d_in[i];
    else if (in_sizes[i] == 1048576) wp = (const float*)d_in[i];
  }
  if (!x || !wq || !wp) {
    x = (const float*)d_in[0]; wq = (const float*)d_in[1]; wp = (const float*)d_in[2];
  }

  float* out = (float*)d_out;            // [4,2048,1024] fp32, written once
  const size_t NE = (size_t)4 * 16 * 2048 * 64;  // 8388608
  bf16* kb = (bf16*)d_ws;                // ws: K(16) + V(16) + y(16) + Q(16) = 64MB
  bf16* vb = kb + NE;
  bf16* yb = vb + NE;
  bf16* qb = yb + NE;

  gemm_qkv<<<dim3(24, 64), 256, 0, stream>>>(x, wq, qb, kb, vb);
  attn<<<dim3(16, 64), 256, 0, stream>>>(qb, kb, vb, yb);
  gemm_proj<<<dim3(8, 64), 256, 0, stream>>>(yb, wp, out);
}

// Round 10
// 278.003 us; speedup vs baseline: 348.9130x; 1.2157x over previous
//
#include <hip/hip_runtime.h>
#include <cstdint>
#include <cstddef>

// Pipeline v4. B=4, T=2048, D=1024, H=16, HD=64. Inputs fp32, output fp32.
// attn v3: no-max softmax in exp2 domain (scores bounded; offset cancels in
// o/l), log2e folded into Q scale, deferred l-reduction.
// GEMMs: if ws_size >= 88MiB, pre-convert inputs to bf16 and use m97-style
// global_load_lds width-16 staging; else fall back to cvt8 register staging.
// ws: K(16) V(16) Q(16) y(16) = 64MB; ext: xb(16.8) wqb(6.3) wpb(2.1).

typedef __bf16 bf16;
typedef __bf16 bf16x8 __attribute__((ext_vector_type(8)));
typedef float  f32x4  __attribute__((ext_vector_type(4)));
typedef float  fvec4  __attribute__((ext_vector_type(4)));
typedef unsigned u32x4 __attribute__((ext_vector_type(4)));

typedef __attribute__((address_space(1))) const void global_cv;
typedef __attribute__((address_space(3))) void lds_v;

#define MFMA16(a, b, c) __builtin_amdgcn_mfma_f32_16x16x32_bf16((a), (b), (c), 0, 0, 0)

// Q scale: 1/sqrt(64) * log2(e)  (softmax done in exp2 domain)
#define QSCALE 0.18033688f

__device__ __forceinline__ void async_ld16(const bf16* g, bf16* l) {
  // gfx950 16B direct global->LDS; dest = wave-uniform base + lane*16.
  __builtin_amdgcn_global_load_lds((global_cv*)g, (lds_v*)l, 16, 0, 0);
}

// XOR chunk swizzle for [rows][64] bf16 LDS tiles.
__device__ __forceinline__ int swz_off(int row, int col) {
  int sr = (row & 7) ^ ((row >> 3) & 7);
  return row * 64 + ((((col >> 3) ^ sr) & 7) * 8) + (col & 7);
}

__device__ __forceinline__ bf16x8 cvt8(const float* p) {
  fvec4 u = *(const fvec4*)p;
  fvec4 v = *(const fvec4*)(p + 4);
  bf16x8 r;
  r[0] = (bf16)u[0]; r[1] = (bf16)u[1]; r[2] = (bf16)u[2]; r[3] = (bf16)u[3];
  r[4] = (bf16)v[0]; r[5] = (bf16)v[1]; r[6] = (bf16)v[2]; r[7] = (bf16)v[3];
  return r;
}

// ---------------------------------------------------------------------------
// fp32 -> bf16 bulk convert (8 elems/thread).
// ---------------------------------------------------------------------------
__global__ void cvt_f32_bf16(const float* __restrict__ s, bf16* __restrict__ d,
                             int n8) {
  int i = blockIdx.x * 256 + threadIdx.x;
  if (i < n8) *(bf16x8*)(d + (size_t)i * 8) = cvt8(s + (size_t)i * 8);
}

// ---------------------------------------------------------------------------
// Shared epilogue helpers
// ---------------------------------------------------------------------------
__device__ __forceinline__ void qkv_scatter(const f32x4 acc[4][4], int m0, int n0,
                                            int wm, int wn, int quad, int l15,
                                            bf16* Qo, bf16* Ko, bf16* Vo) {
  const int which = n0 >> 10;  // 0=Q 1=K 2=V
  bf16* dst = (which == 0) ? Qo : (which == 1) ? Ko : Vo;
  const float scale = (which == 0) ? QSCALE : 1.0f;
#pragma unroll
  for (int i = 0; i < 4; ++i) {
    const int m = m0 + wm + i * 16 + quad * 4;
#pragma unroll
    for (int j = 0; j < 4; ++j) {
      const int n  = n0 + wn + j * 16 + l15;
      const int n1 = n & 1023;
      const int h  = n1 >> 6;
      const int d  = n1 & 63;
#pragma unroll
      for (int r = 0; r < 4; ++r) {
        const int mm = m + r;
        const int b  = mm >> 11;
        const int t  = mm & 2047;
        dst[(((size_t)(b * 16 + h)) * 2048 + t) * 64 + d] =
            (bf16)(acc[i][j][r] * scale);
      }
    }
  }
}

// ---------------------------------------------------------------------------
// QKV GEMM, bf16 async-staging variant (plan A). grid (24,64).
// ---------------------------------------------------------------------------
__global__ __launch_bounds__(256, 2)
void gemm_qkv_a(const bf16* __restrict__ A, const bf16* __restrict__ B,
                bf16* __restrict__ Qo, bf16* __restrict__ Ko,
                bf16* __restrict__ Vo) {
  __shared__ __align__(16) bf16 As[128 * 32];
  __shared__ __align__(16) bf16 Bs[128 * 32];
  const int K = 1024;

  const int tid  = threadIdx.x;
  const int lane = tid & 63;
  const int wave = tid >> 6;
  const int quad = lane >> 4;
  const int l15  = lane & 15;
  const int wm   = (wave >> 1) * 64;
  const int wn   = (wave & 1) * 64;
  const int m0   = blockIdx.y * 128;
  const int n0   = blockIdx.x * 128;

  f32x4 acc[4][4];
#pragma unroll
  for (int i = 0; i < 4; ++i)
#pragma unroll
    for (int j = 0; j < 4; ++j) acc[i][j] = f32x4{0.f, 0.f, 0.f, 0.f};

  const int r0 = tid >> 2;
  const int c0 = (tid & 3) * 8;
  const bf16* ag0 = A + (size_t)(m0 + r0) * K + c0;
  const bf16* ag1 = A + (size_t)(m0 + 64 + r0) * K + c0;
  const bf16* bg0 = B + (size_t)(n0 + r0) * K + c0;
  const bf16* bg1 = B + (size_t)(n0 + 64 + r0) * K + c0;
  const int lo0 = (wave * 64) * 8;        // wave-uniform LDS elem offset
  const int lo1 = (256 + wave * 64) * 8;

  for (int k0 = 0; k0 < K; k0 += 32) {
    __syncthreads();
    async_ld16(ag0 + k0, As + lo0);
    async_ld16(ag1 + k0, As + lo1);
    async_ld16(bg0 + k0, Bs + lo0);
    async_ld16(bg1 + k0, Bs + lo1);
    __syncthreads();

    bf16x8 af[4], bfr[4];
#pragma unroll
    for (int i = 0; i < 4; ++i)
      af[i] = *(const bf16x8*)(As + (wm + i * 16 + l15) * 32 + quad * 8);
#pragma unroll
    for (int j = 0; j < 4; ++j)
      bfr[j] = *(const bf16x8*)(Bs + (wn + j * 16 + l15) * 32 + quad * 8);
#pragma unroll
    for (int i = 0; i < 4; ++i)
#pragma unroll
      for (int j = 0; j < 4; ++j)
        acc[i][j] = MFMA16(af[i], bfr[j], acc[i][j]);
  }
  qkv_scatter(acc, m0, n0, wm, wn, quad, l15, Qo, Ko, Vo);
}

// ---------------------------------------------------------------------------
// QKV GEMM, fp32 cvt8 register-staging variant (plan B fallback). grid (24,64).
// ---------------------------------------------------------------------------
__global__ __launch_bounds__(256, 2)
void gemm_qkv_f(const float* __restrict__ A, const float* __restrict__ B,
                bf16* __restrict__ Qo, bf16* __restrict__ Ko,
                bf16* __restrict__ Vo) {
  __shared__ __align__(16) bf16 As[128 * 32];
  __shared__ __align__(16) bf16 Bs[128 * 32];
  const int K = 1024;

  const int tid  = threadIdx.x;
  const int lane = tid & 63;
  const int wave = tid >> 6;
  const int quad = lane >> 4;
  const int l15  = lane & 15;
  const int wm   = (wave >> 1) * 64;
  const int wn   = (wave & 1) * 64;
  const int m0   = blockIdx.y * 128;
  const int n0   = blockIdx.x * 128;

  f32x4 acc[4][4];
#pragma unroll
  for (int i = 0; i < 4; ++i)
#pragma unroll
    for (int j = 0; j < 4; ++j) acc[i][j] = f32x4{0.f, 0.f, 0.f, 0.f};

  const int r0 = tid >> 2;
  const int c0 = (tid & 3) * 8;
  const size_t aoff0 = (size_t)(m0 + r0) * K + c0;
  const size_t aoff1 = (size_t)(m0 + 64 + r0) * K + c0;
  const size_t boff0 = (size_t)(n0 + r0) * K + c0;
  const size_t boff1 = (size_t)(n0 + 64 + r0) * K + c0;

  for (int k0 = 0; k0 < K; k0 += 32) {
    bf16x8 va0 = cvt8(A + aoff0 + k0);
    bf16x8 va1 = cvt8(A + aoff1 + k0);
    bf16x8 vb0 = cvt8(B + boff0 + k0);
    bf16x8 vb1 = cvt8(B + boff1 + k0);
    __syncthreads();
    *(bf16x8*)(As + tid * 8)        = va0;
    *(bf16x8*)(As + 2048 + tid * 8) = va1;
    *(bf16x8*)(Bs + tid * 8)        = vb0;
    *(bf16x8*)(Bs + 2048 + tid * 8) = vb1;
    __syncthreads();

    bf16x8 af[4], bfr[4];
#pragma unroll
    for (int i = 0; i < 4; ++i)
      af[i] = *(const bf16x8*)(As + (wm + i * 16 + l15) * 32 + quad * 8);
#pragma unroll
    for (int j = 0; j < 4; ++j)
      bfr[j] = *(const bf16x8*)(Bs + (wn + j * 16 + l15) * 32 + quad * 8);
#pragma unroll
    for (int i = 0; i < 4; ++i)
#pragma unroll
      for (int j = 0; j < 4; ++j)
        acc[i][j] = MFMA16(af[i], bfr[j], acc[i][j]);
  }
  qkv_scatter(acc, m0, n0, wm, wn, quad, l15, Qo, Ko, Vo);
}

// ---------------------------------------------------------------------------
// Flash attention v3, causal. Block p in grid (16,64) handles q-tiles
// {p, 31-p}. No-max softmax: Q carries 1/8*log2e, p=exp2(s) directly
// (scores bounded, offset cancels in o/l); per-lane l accumulated across
// tiles, single 16-lane reduce at the end. Double-buffered LDS + prefetch.
// ---------------------------------------------------------------------------
__global__ __launch_bounds__(256, 2)
void attn(const bf16* __restrict__ Q, const bf16* __restrict__ Kk,
          const bf16* __restrict__ V, bf16* __restrict__ Y) {
  __shared__ __align__(16) bf16 Ks[2][64 * 64];    // [kv][d] swizzled
  __shared__ __align__(16) bf16 Vt[2][64 * 64];    // [d][kv] swizzled
  __shared__ __align__(16) bf16 Ps[4 * 16 * 64];   // per-wave P strips

  const int tid  = threadIdx.x;
  const int wave = tid >> 6;
  const int lane = tid & 63;
  const int quad = lane >> 4;
  const int l15  = lane & 15;
  const int bh   = blockIdx.y;
  const int b    = bh >> 4;
  const int h    = bh & 15;
  const bf16* Qb = Q  + (size_t)bh * (2048 * 64);
  const bf16* Kb = Kk + (size_t)bh * (2048 * 64);
  const bf16* Vb = V  + (size_t)bh * (2048 * 64);
  bf16* Pw = Ps + wave * (16 * 64);

  const int kr = tid >> 2;          // K staging: row 0..63
  const int kc = (tid & 3) * 16;    // K staging: col group
  const int vp = tid >> 3;          // V staging: row-pair 0..31
  const int vc8 = (tid & 7) * 8;    // V staging: col chunk base

  const float NEG = -1e30f;

#pragma unroll 1
  for (int pass = 0; pass < 2; ++pass) {
    const int qt = pass ? (31 - (int)blockIdx.x) : (int)blockIdx.x;
    const int q0 = qt * 64;

    bf16x8 qa[2];
#pragma unroll
    for (int t = 0; t < 2; ++t)
      qa[t] = *(const bf16x8*)(Qb + (size_t)(q0 + wave * 16 + l15) * 64 + t * 32 + quad * 8);

    f32x4 l_run = {0.f, 0.f, 0.f, 0.f};
    f32x4 o[4];
#pragma unroll
    for (int j = 0; j < 4; ++j) o[j] = f32x4{0.f, 0.f, 0.f, 0.f};

    // prefetch tile 0
    bf16x8 pk0 = *(const bf16x8*)(Kb + (size_t)kr * 64 + kc);
    bf16x8 pk1 = *(const bf16x8*)(Kb + (size_t)kr * 64 + kc + 8);
    u32x4  pva = *(const u32x4*)(Vb + (size_t)(2 * vp) * 64 + vc8);
    u32x4  pvb = *(const u32x4*)(Vb + (size_t)(2 * vp + 1) * 64 + vc8);

#pragma unroll 1
    for (int kt = 0; kt <= qt; ++kt) {
      const int cur = kt & 1;
      const int k0  = kt * 64;
      *(bf16x8*)(Ks[cur] + swz_off(kr, kc))     = pk0;
      *(bf16x8*)(Ks[cur] + swz_off(kr, kc + 8)) = pk1;
      {
        unsigned* vt32 = (unsigned*)Vt[cur];
#pragma unroll
        for (int i = 0; i < 8; ++i) {
          unsigned lo = (i & 1) ? (pva[i >> 1] >> 16) : (pva[i >> 1] & 0xFFFFu);
          unsigned hi = (i & 1) ? (pvb[i >> 1] >> 16) : (pvb[i >> 1] & 0xFFFFu);
          vt32[swz_off(vc8 + i, 2 * vp) >> 1] = lo | (hi << 16);
        }
      }
      __syncthreads();

      if (kt < qt) {
        const int kn = k0 + 64;
        pk0 = *(const bf16x8*)(Kb + (size_t)(kn + kr) * 64 + kc);
        pk1 = *(const bf16x8*)(Kb + (size_t)(kn + kr) * 64 + kc + 8);
        pva = *(const u32x4*)(Vb + (size_t)(kn + 2 * vp) * 64 + vc8);
        pvb = *(const u32x4*)(Vb + (size_t)(kn + 2 * vp + 1) * 64 + vc8);
      }

      // S = Q K^T (already log2-domain via QSCALE)
      f32x4 s[4];
#pragma unroll
      for (int j = 0; j < 4; ++j) {
        const int kvr = j * 16 + l15;
        bf16x8 k0f = *(const bf16x8*)(Ks[cur] + swz_off(kvr, quad * 8));
        bf16x8 k1f = *(const bf16x8*)(Ks[cur] + swz_off(kvr, 32 + quad * 8));
        f32x4 z = {0.f, 0.f, 0.f, 0.f};
        z = MFMA16(qa[0], k0f, z);
        z = MFMA16(qa[1], k1f, z);
        s[j] = z;
      }

      if (kt == qt) {  // diagonal: causal mask
#pragma unroll
        for (int j = 0; j < 4; ++j) {
          const int kvg = k0 + j * 16 + l15;
#pragma unroll
          for (int r = 0; r < 4; ++r) {
            const int qg = q0 + wave * 16 + quad * 4 + r;
            if (kvg > qg) s[j][r] = NEG;
          }
        }
      }

      // p = exp2(s); accumulate per-lane l partials
#pragma unroll
      for (int j = 0; j < 4; ++j)
#pragma unroll
        for (int r = 0; r < 4; ++r) {
          float p = exp2f(s[j][r]);
          s[j][r] = p;
          l_run[r] += p;
        }

      // P: C-layout -> per-wave LDS strip -> A-operand frags
#pragma unroll
      for (int j = 0; j < 4; ++j)
#pragma unroll
        for (int r = 0; r < 4; ++r)
          Pw[swz_off(quad * 4 + r, j * 16 + l15)] = (bf16)s[j][r];

      bf16x8 pf0 = *(const bf16x8*)(Pw + swz_off(l15, quad * 8));
      bf16x8 pf1 = *(const bf16x8*)(Pw + swz_off(l15, 32 + quad * 8));
#pragma unroll
      for (int j = 0; j < 4; ++j) {
        const int d = j * 16 + l15;
        bf16x8 vf0 = *(const bf16x8*)(Vt[cur] + swz_off(d, quad * 8));
        bf16x8 vf1 = *(const bf16x8*)(Vt[cur] + swz_off(d, 32 + quad * 8));
        o[j] = MFMA16(pf0, vf0, o[j]);
        o[j] = MFMA16(pf1, vf1, o[j]);
      }
    }

    // one deferred 16-lane reduce for l (lanes of a quad hold same rows)
#pragma unroll
    for (int msk = 1; msk < 16; msk <<= 1)
#pragma unroll
      for (int r = 0; r < 4; ++r) l_run[r] += __shfl_xor(l_run[r], msk);

#pragma unroll
    for (int j = 0; j < 4; ++j) {
      const int dcol = h * 64 + j * 16 + l15;
#pragma unroll
      for (int r = 0; r < 4; ++r) {
        const int trow = q0 + wave * 16 + quad * 4 + r;
        Y[((size_t)b * 2048 + trow) * 1024 + dcol] = (bf16)(o[j][r] / l_run[r]);
      }
    }
    __syncthreads();  // protect LDS buffers across passes
  }
}

// ---------------------------------------------------------------------------
// Projection GEMM, bf16 async variant (plan A): out fp32 = y(bf16)*wpb^T.
// grid (8,64).
// ---------------------------------------------------------------------------
__global__ __launch_bounds__(256, 2)
void gemm_proj_a(const bf16* __restrict__ A, const bf16* __restrict__ B,
                 float* __restrict__ C) {
  __shared__ __align__(16) bf16 As[128 * 32];
  __shared__ __align__(16) bf16 Bs[128 * 32];
  const int K = 1024, N = 1024;

  const int tid  = threadIdx.x;
  const int lane = tid & 63;
  const int wave = tid >> 6;
  const int quad = lane >> 4;
  const int l15  = lane & 15;
  const int wm   = (wave >> 1) * 64;
  const int wn   = (wave & 1) * 64;
  const int m0   = blockIdx.y * 128;
  const int n0   = blockIdx.x * 128;

  f32x4 acc[4][4];
#pragma unroll
  for (int i = 0; i < 4; ++i)
#pragma unroll
    for (int j = 0; j < 4; ++j) acc[i][j] = f32x4{0.f, 0.f, 0.f, 0.f};

  const int r0 = tid >> 2;
  const int c0 = (tid & 3) * 8;
  const bf16* ag0 = A + (size_t)(m0 + r0) * K + c0;
  const bf16* ag1 = A + (size_t)(m0 + 64 + r0) * K + c0;
  const bf16* bg0 = B + (size_t)(n0 + r0) * K + c0;
  const bf16* bg1 = B + (size_t)(n0 + 64 + r0) * K + c0;
  const int lo0 = (wave * 64) * 8;
  const int lo1 = (256 + wave * 64) * 8;

  for (int k0 = 0; k0 < K; k0 += 32) {
    __syncthreads();
    async_ld16(ag0 + k0, As + lo0);
    async_ld16(ag1 + k0, As + lo1);
    async_ld16(bg0 + k0, Bs + lo0);
    async_ld16(bg1 + k0, Bs + lo1);
    __syncthreads();

    bf16x8 af[4], bfr[4];
#pragma unroll
    for (int i = 0; i < 4; ++i)
      af[i] = *(const bf16x8*)(As + (wm + i * 16 + l15) * 32 + quad * 8);
#pragma unroll
    for (int j = 0; j < 4; ++j)
      bfr[j] = *(const bf16x8*)(Bs + (wn + j * 16 + l15) * 32 + quad * 8);
#pragma unroll
    for (int i = 0; i < 4; ++i)
#pragma unroll
      for (int j = 0; j < 4; ++j)
        acc[i][j] = MFMA16(af[i], bfr[j], acc[i][j]);
  }

#pragma unroll
  for (int i = 0; i < 4; ++i) {
    const int m = m0 + wm + i * 16 + quad * 4;
#pragma unroll
    for (int j = 0; j < 4; ++j) {
      const int n = n0 + wn + j * 16 + l15;
#pragma unroll
      for (int r = 0; r < 4; ++r)
        C[(size_t)(m + r) * N + n] = acc[i][j][r];
    }
  }
}

// ---------------------------------------------------------------------------
// Projection GEMM, fp32-B fallback (plan B). grid (8,64).
// ---------------------------------------------------------------------------
__global__ __launch_bounds__(256, 2)
void gemm_proj_f(const bf16* __restrict__ A, const float* __restrict__ B,
                 float* __restrict__ C) {
  __shared__ __align__(16) bf16 As[128 * 32];
  __shared__ __align__(16) bf16 Bs[128 * 32];
  const int K = 1024, N = 1024;

  const int tid  = threadIdx.x;
  const int lane = tid & 63;
  const int wave = tid >> 6;
  const int quad = lane >> 4;
  const int l15  = lane & 15;
  const int wm   = (wave >> 1) * 64;
  const int wn   = (wave & 1) * 64;
  const int m0   = blockIdx.y * 128;
  const int n0   = blockIdx.x * 128;

  f32x4 acc[4][4];
#pragma unroll
  for (int i = 0; i < 4; ++i)
#pragma unroll
    for (int j = 0; j < 4; ++j) acc[i][j] = f32x4{0.f, 0.f, 0.f, 0.f};

  const int r0 = tid >> 2;
  const int c0 = (tid & 3) * 8;
  const size_t aoff0 = (size_t)(m0 + r0) * K + c0;
  const size_t aoff1 = (size_t)(m0 + 64 + r0) * K + c0;
  const size_t boff0 = (size_t)(n0 + r0) * K + c0;
  const size_t boff1 = (size_t)(n0 + 64 + r0) * K + c0;

  for (int k0 = 0; k0 < K; k0 += 32) {
    bf16x8 va0 = *(const bf16x8*)(A + aoff0 + k0);
    bf16x8 va1 = *(const bf16x8*)(A + aoff1 + k0);
    bf16x8 vb0 = cvt8(B + boff0 + k0);
    bf16x8 vb1 = cvt8(B + boff1 + k0);
    __syncthreads();
    *(bf16x8*)(As + tid * 8)        = va0;
    *(bf16x8*)(As + 2048 + tid * 8) = va1;
    *(bf16x8*)(Bs + tid * 8)        = vb0;
    *(bf16x8*)(Bs + 2048 + tid * 8) = vb1;
    __syncthreads();

    bf16x8 af[4], bfr[4];
#pragma unroll
    for (int i = 0; i < 4; ++i)
      af[i] = *(const bf16x8*)(As + (wm + i * 16 + l15) * 32 + quad * 8);
#pragma unroll
    for (int j = 0; j < 4; ++j)
      bfr[j] = *(const bf16x8*)(Bs + (wn + j * 16 + l15) * 32 + quad * 8);
#pragma unroll
    for (int i = 0; i < 4; ++i)
#pragma unroll
      for (int j = 0; j < 4; ++j)
        acc[i][j] = MFMA16(af[i], bfr[j], acc[i][j]);
  }

#pragma unroll
  for (int i = 0; i < 4; ++i) {
    const int m = m0 + wm + i * 16 + quad * 4;
#pragma unroll
    for (int j = 0; j < 4; ++j) {
      const int n = n0 + wn + j * 16 + l15;
#pragma unroll
      for (int r = 0; r < 4; ++r)
        C[(size_t)(m + r) * N + n] = acc[i][j][r];
    }
  }
}

// ---------------------------------------------------------------------------
extern "C" void kernel_launch(void* const* d_in, const int* in_sizes, int n_in,
                              void* d_out, int out_size, void* d_ws, size_t ws_size,
                              hipStream_t stream) {
  const float* x  = nullptr;   // 8388608 elems
  const float* wq = nullptr;   // 3145728
  const float* wp = nullptr;   // 1048576
  for (int i = 0; i < n_in; ++i) {
    if      (in_sizes[i] == 8388608) x  = (const float*)d_in[i];
    else if (in_sizes[i] == 3145728) wq = (const float*)d_in[i];
    else if (in_sizes[i] == 1048576) wp = (const float*)d_in[i];
  }
  if (!x || !wq || !wp) {
    x = (const float*)d_in[0]; wq = (const float*)d_in[1]; wp = (const float*)d_in[2];
  }

  float* out = (float*)d_out;            // [4,2048,1024] fp32, written once
  const size_t NE = (size_t)4 * 16 * 2048 * 64;  // 8388608
  bf16* kb = (bf16*)d_ws;                // base 64MB: K,V,Q,y
  bf16* vb = kb + NE;
  bf16* qb = vb + NE;
  bf16* yb = qb + NE;
  // extended region (bf16 copies of inputs)
  bf16* xb  = yb + NE;                   // 8388608 elems
  bf16* wqb = xb + 8388608;              // 3145728
  bf16* wpb = wqb + 3145728;             // 1048576
  const size_t need = (4 * NE + 8388608 + 3145728 + 1048576) * sizeof(bf16);
  const bool ext = ws_size >= need;      // deterministic -> graph-safe

  if (ext) {
    cvt_f32_bf16<<<(8388608 / 8 + 255) / 256, 256, 0, stream>>>(x, xb, 8388608 / 8);
    cvt_f32_bf16<<<(3145728 / 8 + 255) / 256, 256, 0, stream>>>(wq, wqb, 3145728 / 8);
    cvt_f32_bf16<<<(1048576 / 8 + 255) / 256, 256, 0, stream>>>(wp, wpb, 1048576 / 8);
    gemm_qkv_a<<<dim3(24, 64), 256, 0, stream>>>(xb, wqb, qb, kb, vb);
  } else {
    gemm_qkv_f<<<dim3(24, 64), 256, 0, stream>>>(x, wq, qb, kb, vb);
  }

  attn<<<dim3(16, 64), 256, 0, stream>>>(qb, kb, vb, yb);

  if (ext) {
    gemm_proj_a<<<dim3(8, 64), 256, 0, stream>>>(yb, wpb, out);
  } else {
    gemm_proj_f<<<dim3(8, 64), 256, 0, stream>>>(yb, wp, out);
  }
}